// Round 11
// baseline (850.124 us; speedup 1.0000x reference)
//
#include <hip/hip_runtime.h>

// ---------------- types ----------------
typedef __bf16 bf16x8 __attribute__((ext_vector_type(8)));
typedef float f32x4 __attribute__((ext_vector_type(4)));

__device__ __forceinline__ unsigned short f2bf(float f) {
    unsigned int u = __builtin_bit_cast(unsigned int, f);
    u += 0x7FFFu + ((u >> 16) & 1u);
    return (unsigned short)(u >> 16);
}

// ---------------- weight f32 -> bf16 conversion ----------------
__global__ void cvt_kernel(const float* __restrict__ in,
                           unsigned short* __restrict__ out, long n4) {
    long i = (long)blockIdx.x * blockDim.x + threadIdx.x;
    long stride = (long)gridDim.x * blockDim.x;
    for (; i < n4; i += stride) {
        float4 v = ((const float4*)in)[i];
        ushort4 o;
        o.x = f2bf(v.x); o.y = f2bf(v.y); o.z = f2bf(v.z); o.w = f2bf(v.w);
        ((ushort4*)out)[i] = o;
    }
}

// ---------------- fused 2-token attention -> h0 (bf16) ----------------
__global__ __launch_bounds__(256) void attn_kernel(
    const float* __restrict__ x1, const float* __restrict__ x2,
    unsigned short* __restrict__ h) {
    const int D = 1024;
    const int lane = threadIdx.x & 63;
    const int wave = threadIdx.x >> 6;
    const long row = (long)blockIdx.x * 4 + wave;
    const float4* p1 = (const float4*)(x1 + row * D);
    const float4* p2 = (const float4*)(x2 + row * D);
    float4 v1[4], v2[4];
    float s11 = 0.f, s12 = 0.f, s22 = 0.f;
#pragma unroll
    for (int j = 0; j < 4; ++j) {
        v1[j] = p1[lane + 64 * j];
        v2[j] = p2[lane + 64 * j];
        s11 += v1[j].x * v1[j].x + v1[j].y * v1[j].y + v1[j].z * v1[j].z + v1[j].w * v1[j].w;
        s12 += v1[j].x * v2[j].x + v1[j].y * v2[j].y + v1[j].z * v2[j].z + v1[j].w * v2[j].w;
        s22 += v2[j].x * v2[j].x + v2[j].y * v2[j].y + v2[j].z * v2[j].z + v2[j].w * v2[j].w;
    }
#pragma unroll
    for (int off = 1; off < 64; off <<= 1) {
        s11 += __shfl_xor(s11, off);
        s12 += __shfl_xor(s12, off);
        s22 += __shfl_xor(s22, off);
    }
    const float a00 = 1.f / (1.f + expf((s12 - s11) * (1.f / 32.f)));
    const float a10 = 1.f / (1.f + expf((s22 - s12) * (1.f / 32.f)));
    const float a01 = 1.f - a00, a11 = 1.f - a10;
    unsigned short* h0 = h + row * 2048;
#pragma unroll
    for (int j = 0; j < 4; ++j) {
        const int f = lane + 64 * j;
        ushort4 o0, o1;
        o0.x = f2bf(a00 * v1[j].x + a01 * v2[j].x);
        o0.y = f2bf(a00 * v1[j].y + a01 * v2[j].y);
        o0.z = f2bf(a00 * v1[j].z + a01 * v2[j].z);
        o0.w = f2bf(a00 * v1[j].w + a01 * v2[j].w);
        o1.x = f2bf(a10 * v1[j].x + a11 * v2[j].x);
        o1.y = f2bf(a10 * v1[j].y + a11 * v2[j].y);
        o1.z = f2bf(a10 * v1[j].z + a11 * v2[j].z);
        o1.w = f2bf(a10 * v1[j].w + a11 * v2[j].w);
        ((ushort4*)(h0))[f] = o0;
        ((ushort4*)(h0 + 1024))[f] = o1;
    }
}

// ---- 256x128 GEMM, 4-wave blocks, 2 independent blocks/CU -----------------
// 4 waves (2Mx2N), wave-tile 128x64 (acc 8x4 f32x4 = 128 AGPR). BK=32.
// LDS: 3 slots x 24 KiB (A 16K [256x32] | B 8K [128x32], 64B pitch) = 72 KiB
// -> 2 blocks/CU, each SIMD hosts 2 waves from 2 INDEPENDENT barrier domains
// (desync: one block's MFMA overlaps the other's LDS reads/staging).
// One phase per K-tile: {stage t+2 (6 gload_lds); 12 ds_read; 32 MFMA;
// VMW(6); BAR}. st_16x32 swizzle on stage-source AND read addr (R10-proven).
#define BAR   __builtin_amdgcn_s_barrier()
#define VMW6  asm volatile("s_waitcnt vmcnt(6)" ::: "memory")
#define VMW0  asm volatile("s_waitcnt vmcnt(0)" ::: "memory")
#define PRIO1 __builtin_amdgcn_s_setprio(1)
#define PRIO0 __builtin_amdgcn_s_setprio(0)

template <bool RELU, typename OT>
__global__ __launch_bounds__(256, 2) void gemm4w(
    const unsigned short* __restrict__ A,   // [M,K] bf16 (activations)
    const unsigned short* __restrict__ Bw,  // [N,K] bf16 (weights)
    const float* __restrict__ bias,         // [N]
    OT* __restrict__ C,                     // [M,N]
    int N, int K) {
    __shared__ __align__(16) unsigned short lds[36864];  // 72 KiB
    const int tid = threadIdx.x;
    const int lane = tid & 63, wave = tid >> 6;
    const int wm = wave >> 1, wn = wave & 1;
    const int fr = lane & 15, fq = lane >> 4;

    // XCD swizzle (grid % 8 == 0); bm fastest -> each XCD owns few B-panels.
    const int cpx = (int)gridDim.x >> 3;
    const int swz = ((int)blockIdx.x & 7) * cpx + ((int)blockIdx.x >> 3);
    const int bm = swz & 63;
    const int bn = swz >> 6;
    const long m0 = (long)bm * 256, n0 = (long)bn * 128;
    const long rowb = (long)K * 2;

    // read addressing: slot*24576 + region + row*64 + (fq*16 ^ flip)
    const int flip = ((fr >> 3) & 1) << 5;
    const int lbase = fr * 64 + ((fq * 16) ^ flip);
    const int aRd = wm * 8192 + lbase;            // + mq*1024 (mq 0..7)
    const int bRd = 16384 + wn * 4096 + lbase;    // + nf*1024 (nf 0..3)
    const char* ldsc = (const char*)lds;

    // staging: 256 thr x 16 B x 6 passes = 24 KiB per K-tile.
    // pass p: row = p*64 + tid/4 (A: p 0..3; B: p 0..1), linear LDS dest
    // row*64 + (tid&3)*16, pre-swizzled global source column.
    const int srow = tid >> 2;
    const int scol = ((tid & 3) << 4) ^ (((tid >> 5) & 1) << 5);
    const char* Abl = (const char*)A + m0 * rowb + scol;
    const char* Bbl = (const char*)Bw + n0 * rowb + scol;
    const int dA = srow * 64 + (tid & 3) * 16;           // + p*4096
    const int dB = 16384 + srow * 64 + (tid & 3) * 16;   // + p*4096

    auto gl = [&](const char* src, int dst) {
        __builtin_amdgcn_global_load_lds(
            (const __attribute__((address_space(1))) void*)src,
            (__attribute__((address_space(3))) void*)((char*)lds + dst),
            16, 0, 0);
    };
    auto stage = [&](int kt, int slot) {
        const long ko = (long)kt * 64;
        const int sb = slot * 24576;
#pragma unroll
        for (int p = 0; p < 4; ++p)
            gl(Abl + (long)(p * 64 + srow) * rowb + ko, sb + dA + p * 4096);
#pragma unroll
        for (int p = 0; p < 2; ++p)
            gl(Bbl + (long)(p * 64 + srow) * rowb + ko, sb + dB + p * 4096);
    };

    f32x4 acc[8][4] = {};
    bf16x8 Af[8], Bf[4];

    // ---- prologue: t0 -> slot0, t1 -> slot1; retire t0; barrier ----
    stage(0, 0);
    stage(1, 1);
    VMW6;
    BAR;

    const int NT = K >> 5;   // K-tiles of 32
    int sl = 0;
    for (int t = 0; t < NT; ++t) {
        const bool g = (t + 2 < NT);
        if (g) { const int ss = (sl == 0) ? 2 : sl - 1; stage(t + 2, ss); }
        const int sb = sl * 24576;
#pragma unroll
        for (int mq = 0; mq < 8; ++mq)
            Af[mq] = *(const bf16x8*)(ldsc + sb + aRd + mq * 1024);
#pragma unroll
        for (int nf = 0; nf < 4; ++nf)
            Bf[nf] = *(const bf16x8*)(ldsc + sb + bRd + nf * 1024);
        PRIO1;
#pragma unroll
        for (int nf = 0; nf < 4; ++nf)
#pragma unroll
            for (int mq = 0; mq < 8; ++mq)
                acc[mq][nf] = __builtin_amdgcn_mfma_f32_16x16x32_bf16(
                    Bf[nf], Af[mq], acc[mq][nf], 0, 0, 0);
        PRIO0;
        if (g) { VMW6; } else { VMW0; }
        BAR;
        sl = (sl == 2) ? 0 : sl + 1;
    }

    // ---- epilogue: swapped layout => lane owns row (fr) x 4 consecutive cols
    const long crow0 = m0 + wm * 128 + fr;
    const long ccol0 = n0 + wn * 64 + fq * 4;
#pragma unroll
    for (int m = 0; m < 8; ++m) {
        const long rb = (crow0 + m * 16) * N;
#pragma unroll
        for (int n = 0; n < 4; ++n) {
            const float4 bv = *(const float4*)(bias + ccol0 + n * 16);
            float v0 = acc[m][n][0] + bv.x;
            float v1 = acc[m][n][1] + bv.y;
            float v2 = acc[m][n][2] + bv.z;
            float v3 = acc[m][n][3] + bv.w;
            if (RELU) {
                v0 = v0 > 0.f ? v0 : 0.f; v1 = v1 > 0.f ? v1 : 0.f;
                v2 = v2 > 0.f ? v2 : 0.f; v3 = v3 > 0.f ? v3 : 0.f;
            }
            if constexpr (sizeof(OT) == 2) {
                uint2 oo;
                oo.x = (unsigned)f2bf(v0) | ((unsigned)f2bf(v1) << 16);
                oo.y = (unsigned)f2bf(v2) | ((unsigned)f2bf(v3) << 16);
                *(uint2*)((unsigned short*)C + rb + ccol0 + n * 16) = oo;
            } else {
                *(float4*)((float*)C + rb + ccol0 + n * 16) =
                    make_float4(v0, v1, v2, v3);
            }
        }
    }
}

// ---------------- launch ----------------
extern "C" void kernel_launch(void* const* d_in, const int* in_sizes, int n_in,
                              void* d_out, int out_size, void* d_ws, size_t ws_size,
                              hipStream_t stream) {
    const float* x1 = (const float*)d_in[0];
    const float* x2 = (const float*)d_in[1];
    const float* Ws = (const float*)d_in[2];   // [4,2048,2048]
    const float* bs = (const float*)d_in[3];   // [4,2048]
    const float* Wl = (const float*)d_in[4];   // [1024,2048]
    const float* bl = (const float*)d_in[5];   // [1024]
    float* out = (float*)d_out;                // [16384,1024]

    char* ws = (char*)d_ws;
    unsigned short* hA  = (unsigned short*)(ws);                  // 64 MiB
    unsigned short* hB  = (unsigned short*)(ws + (67108864L));    // 64 MiB
    unsigned short* Wbf = (unsigned short*)(ws + (134217728L));   // 32 MiB
    unsigned short* Wlb = (unsigned short*)(ws + (167772160L));   // 4 MiB

    cvt_kernel<<<2048, 256, 0, stream>>>(Ws, Wbf, 4L * 2048 * 2048 / 4);
    cvt_kernel<<<512, 256, 0, stream>>>(Wl, Wlb, 1024L * 2048 / 4);

    attn_kernel<<<16384 / 4, 256, 0, stream>>>(x1, x2, hA);

    // MLP: 4x relu GEMM (bf16 ping-pong) + final GEMM (f32 out)
    // grid = (M/256) x (N/128): 64*16 = 1024 (layers), 64*8 = 512 (final)
    gemm4w<true, unsigned short><<<1024, 256, 0, stream>>>(hA, Wbf + 0L * 2048 * 2048, bs + 0 * 2048, hB, 2048, 2048);
    gemm4w<true, unsigned short><<<1024, 256, 0, stream>>>(hB, Wbf + 1L * 2048 * 2048, bs + 1 * 2048, hA, 2048, 2048);
    gemm4w<true, unsigned short><<<1024, 256, 0, stream>>>(hA, Wbf + 2L * 2048 * 2048, bs + 2 * 2048, hB, 2048, 2048);
    gemm4w<true, unsigned short><<<1024, 256, 0, stream>>>(hB, Wbf + 3L * 2048 * 2048, bs + 3 * 2048, hA, 2048, 2048);
    gemm4w<false, float><<<512, 256, 0, stream>>>(hA, Wlb, bl, out, 1024, 2048);
}

// Round 12
// 630.744 us; speedup vs baseline: 1.3478x; 1.3478x over previous
//
#include <hip/hip_runtime.h>

// ---------------- types ----------------
typedef __bf16 bf16x8 __attribute__((ext_vector_type(8)));
typedef float f32x4 __attribute__((ext_vector_type(4)));

__device__ __forceinline__ unsigned short f2bf(float f) {
    unsigned int u = __builtin_bit_cast(unsigned int, f);
    u += 0x7FFFu + ((u >> 16) & 1u);
    return (unsigned short)(u >> 16);
}

// ---------------- weight f32 -> bf16 conversion ----------------
__global__ void cvt_kernel(const float* __restrict__ in,
                           unsigned short* __restrict__ out, long n4) {
    long i = (long)blockIdx.x * blockDim.x + threadIdx.x;
    long stride = (long)gridDim.x * blockDim.x;
    for (; i < n4; i += stride) {
        float4 v = ((const float4*)in)[i];
        ushort4 o;
        o.x = f2bf(v.x); o.y = f2bf(v.y); o.z = f2bf(v.z); o.w = f2bf(v.w);
        ((ushort4*)out)[i] = o;
    }
}

// ---------------- fused 2-token attention -> h0 (bf16) ----------------
__global__ __launch_bounds__(256) void attn_kernel(
    const float* __restrict__ x1, const float* __restrict__ x2,
    unsigned short* __restrict__ h) {
    const int D = 1024;
    const int lane = threadIdx.x & 63;
    const int wave = threadIdx.x >> 6;
    const long row = (long)blockIdx.x * 4 + wave;
    const float4* p1 = (const float4*)(x1 + row * D);
    const float4* p2 = (const float4*)(x2 + row * D);
    float4 v1[4], v2[4];
    float s11 = 0.f, s12 = 0.f, s22 = 0.f;
#pragma unroll
    for (int j = 0; j < 4; ++j) {
        v1[j] = p1[lane + 64 * j];
        v2[j] = p2[lane + 64 * j];
        s11 += v1[j].x * v1[j].x + v1[j].y * v1[j].y + v1[j].z * v1[j].z + v1[j].w * v1[j].w;
        s12 += v1[j].x * v2[j].x + v1[j].y * v2[j].y + v1[j].z * v2[j].z + v1[j].w * v2[j].w;
        s22 += v2[j].x * v2[j].x + v2[j].y * v2[j].y + v2[j].z * v2[j].z + v2[j].w * v2[j].w;
    }
#pragma unroll
    for (int off = 1; off < 64; off <<= 1) {
        s11 += __shfl_xor(s11, off);
        s12 += __shfl_xor(s12, off);
        s22 += __shfl_xor(s22, off);
    }
    const float a00 = 1.f / (1.f + expf((s12 - s11) * (1.f / 32.f)));
    const float a10 = 1.f / (1.f + expf((s22 - s12) * (1.f / 32.f)));
    const float a01 = 1.f - a00, a11 = 1.f - a10;
    unsigned short* h0 = h + row * 2048;
#pragma unroll
    for (int j = 0; j < 4; ++j) {
        const int f = lane + 64 * j;
        ushort4 o0, o1;
        o0.x = f2bf(a00 * v1[j].x + a01 * v2[j].x);
        o0.y = f2bf(a00 * v1[j].y + a01 * v2[j].y);
        o0.z = f2bf(a00 * v1[j].z + a01 * v2[j].z);
        o0.w = f2bf(a00 * v1[j].w + a01 * v2[j].w);
        o1.x = f2bf(a10 * v1[j].x + a11 * v2[j].x);
        o1.y = f2bf(a10 * v1[j].y + a11 * v2[j].y);
        o1.z = f2bf(a10 * v1[j].z + a11 * v2[j].z);
        o1.w = f2bf(a10 * v1[j].w + a11 * v2[j].w);
        ((ushort4*)(h0))[f] = o0;
        ((ushort4*)(h0 + 1024))[f] = o1;
    }
}

// ---------------- 256x256 8-phase GEMM: C = act(A[M,K] * Bw[N,K]^T + bias) ----
// R5 structure (best measured) with XCD M-OWNERSHIP swizzle: bn-fastest within
// XCD so XCD k owns bm in [8k,8k+8) -> resident A working set 4 MB (fits L2),
// each A byte fetched by exactly ONE XCD (was: every XCD streams all of A).
#define BAR   __builtin_amdgcn_s_barrier()
#define VMW4  asm volatile("s_waitcnt vmcnt(4)" ::: "memory")
#define VMW0  asm volatile("s_waitcnt vmcnt(0)" ::: "memory")
#define PRIO1 __builtin_amdgcn_s_setprio(1)
#define PRIO0 __builtin_amdgcn_s_setprio(0)

#define MMQ(mb, kk)                                                            \
  _Pragma("unroll") for (int n = 0; n < 4; ++n)                                \
  _Pragma("unroll") for (int mq = 0; mq < 4; ++mq)                             \
    acc[(mb) + mq][n] = __builtin_amdgcn_mfma_f32_16x16x32_bf16(               \
        Bf[n][kk], Af[mq][kk], acc[(mb) + mq][n], 0, 0, 0);

template <bool RELU, typename OT>
__global__ __launch_bounds__(512, 2) void gemm256(
    const unsigned short* __restrict__ A,   // [M,K] bf16 (activations)
    const unsigned short* __restrict__ Bw,  // [N,K] bf16 (weights)
    const float* __restrict__ bias,         // [N]
    OT* __restrict__ C,                     // [M,N]
    int N, int K) {
    __shared__ __align__(16) unsigned short lds[65536];  // 128 KiB: T0|T1
    const int tid = threadIdx.x;
    const int lane = tid & 63, wave = tid >> 6;
    const int wm = wave >> 2, wn = wave & 3;
    const int fr = lane & 15, fq = lane >> 4;

    // XCD M-ownership swizzle: bn fastest within an XCD's contiguous chunk.
    const int nbn = N >> 8;                      // 8 (layers) or 4 (final)
    const int sh = (nbn == 8) ? 3 : 2;
    const int cpx = (int)gridDim.x >> 3;
    const int swz = ((int)blockIdx.x & 7) * cpx + ((int)blockIdx.x >> 3);
    const int bn = swz & (nbn - 1);
    const int bm = swz >> sh;
    const long m0 = (long)bm * 256, n0 = (long)bn * 256;

    // LDS read bases (byte offsets); kk=1 address = kk=0 address ^ 64.
    const int x0 = fq ^ (fr & 7);
    const int lane_base = fr * 128 + x0 * 16;
    const int aBase = wm * 16384 + lane_base;
    const int bBase = 32768 + (wn >> 1) * 16384 + (wn & 1) * 8192 + lane_base;
    const char* ldsc = (const char*)lds;

    // staging: per-lane pre-swizzled global source offset (same for A and B)
    const int l3 = lane >> 3, l7 = lane & 7;
    const long rowb = (long)K * 2;
    const long lane_src = (long)l3 * rowb + ((l7 ^ l3) << 4);
    const char* Abl = (const char*)A + m0 * rowb + lane_src;
    const char* Bbl = (const char*)Bw + n0 * rowb + lane_src;

    auto stage = [&](const char* mb, int matOff, int hf, int kt, int T) {
#pragma unroll
        for (int r = 0; r < 2; ++r) {
            const int W = r * 8 + wave;
            const char* src = mb + (long)(hf * 128 + W * 8) * rowb + kt * 128;
            __builtin_amdgcn_global_load_lds(
                (const __attribute__((address_space(1))) void*)src,
                (__attribute__((address_space(3))) void*)((char*)lds +
                    (T * 65536 + matOff + hf * 16384 + W * 1024)),
                16, 0, 0);
        }
    };

    f32x4 acc[8][4] = {};
    bf16x8 Bf[4][2], Af[4][2];

    auto readBA = [&](int boff, int kk) {   // Bf[.][kk] + Af(m0-3)[kk]: 8 reads
        const int x = kk * 64;
#pragma unroll
        for (int n = 0; n < 4; ++n)
            Bf[n][kk] = *(const bf16x8*)(ldsc + boff + (bBase ^ x) + n * 2048);
#pragma unroll
        for (int m = 0; m < 4; ++m)
            Af[m][kk] = *(const bf16x8*)(ldsc + boff + (aBase ^ x) + m * 2048);
    };
    auto readAH = [&](int boff) {           // Af <- m4-7, both kk: 8 reads
#pragma unroll
        for (int m = 0; m < 4; ++m) {
            Af[m][0] = *(const bf16x8*)(ldsc + boff + aBase + (m + 4) * 2048);
            Af[m][1] = *(const bf16x8*)(ldsc + boff + (aBase ^ 64) + (m + 4) * 2048);
        }
    };

    // ---- prologue: tile0 (A+B) -> T0; tile1 A halves -> T1 ----
    stage(Abl, 0,     0, 0, 0); stage(Abl, 0,     1, 0, 0);
    stage(Bbl, 32768, 0, 0, 0); stage(Bbl, 32768, 1, 0, 0);
    stage(Abl, 0,     0, 1, 1); stage(Abl, 0,     1, 1, 1);
    VMW4;
    BAR;

    const int NT = K >> 6;       // K-tiles
    const int NIT = NT >> 1;     // iterations, 2 K-tiles each
    for (int i = 0; i < NIT; ++i) {
        const int t1 = 2 * i + 1, t2 = t1 + 1, t3 = t1 + 2;
        const bool g = (i + 1 < NIT);

        // ======== T0 half (tile 2i) ========
        // P1: read kk0 frags; stage B(t1)->T1 (T1 old reads drained at prev P7)
        readBA(0, 0);
        stage(Bbl, 32768, 0, t1, 1); stage(Bbl, 32768, 1, t1, 1);
        BAR; PRIO1; MMQ(0, 0); PRIO0; BAR;
        // P2: read kk1 frags (m0-3)
        readBA(0, 1);
        BAR; PRIO1; MMQ(0, 1); PRIO0; BAR;
        // P3: read m4-7 (both kk); full drain BEFORE barrier -> T0 free at P4
        readAH(0);
        asm volatile("s_waitcnt lgkmcnt(0)" ::: "memory");
        BAR; PRIO1; MMQ(4, 0); PRIO0; BAR;
        // P4: stage A(t2)->T0; vmcnt(4) retires A(t1)+B(t1) (ages 4,3 phases)
        if (g) { stage(Abl, 0, 0, t2, 0); stage(Abl, 0, 1, t2, 0); }
        BAR; PRIO1; MMQ(4, 1); PRIO0;
        if (g) { VMW4; } else { VMW0; }
        BAR;

        // ======== T1 half (tile 2i+1) ========
        // P5: read kk0; stage B(t2)->T0
        readBA(65536, 0);
        if (g) { stage(Bbl, 32768, 0, t2, 0); stage(Bbl, 32768, 1, t2, 0); }
        BAR; PRIO1; MMQ(0, 0); PRIO0; BAR;
        // P6: read kk1 (m0-3)
        readBA(65536, 1);
        BAR; PRIO1; MMQ(0, 1); PRIO0; BAR;
        // P7: read m4-7; full drain -> T1 free at P8
        readAH(65536);
        asm volatile("s_waitcnt lgkmcnt(0)" ::: "memory");
        BAR; PRIO1; MMQ(4, 0); PRIO0; BAR;
        // P8: stage A(t3)->T1; vmcnt(4) retires A(t2)+B(t2) (ages 4,3 phases)
        if (g) { stage(Abl, 0, 0, t3, 1); stage(Abl, 0, 1, t3, 1); }
        BAR; PRIO1; MMQ(4, 1); PRIO0;
        if (g) { VMW4; } else { VMW0; }
        BAR;
    }

    // ---- epilogue: swapped layout => lane owns row (fr) x 4 consecutive cols
    const long crow0 = m0 + wm * 128 + fr;
    const long ccol0 = n0 + wn * 64 + fq * 4;
    float4 bv[4];
#pragma unroll
    for (int n = 0; n < 4; ++n) bv[n] = *(const float4*)(bias + ccol0 + n * 16);
#pragma unroll
    for (int m = 0; m < 8; ++m) {
        const long rb = (crow0 + m * 16) * N;
#pragma unroll
        for (int n = 0; n < 4; ++n) {
            float v0 = acc[m][n][0] + bv[n].x;
            float v1 = acc[m][n][1] + bv[n].y;
            float v2 = acc[m][n][2] + bv[n].z;
            float v3 = acc[m][n][3] + bv[n].w;
            if (RELU) {
                v0 = v0 > 0.f ? v0 : 0.f; v1 = v1 > 0.f ? v1 : 0.f;
                v2 = v2 > 0.f ? v2 : 0.f; v3 = v3 > 0.f ? v3 : 0.f;
            }
            if constexpr (sizeof(OT) == 2) {
                uint2 oo;
                oo.x = (unsigned)f2bf(v0) | ((unsigned)f2bf(v1) << 16);
                oo.y = (unsigned)f2bf(v2) | ((unsigned)f2bf(v3) << 16);
                *(uint2*)((unsigned short*)C + rb + ccol0 + n * 16) = oo;
            } else {
                *(float4*)((float*)C + rb + ccol0 + n * 16) =
                    make_float4(v0, v1, v2, v3);
            }
        }
    }
}

// ---------------- launch ----------------
extern "C" void kernel_launch(void* const* d_in, const int* in_sizes, int n_in,
                              void* d_out, int out_size, void* d_ws, size_t ws_size,
                              hipStream_t stream) {
    const float* x1 = (const float*)d_in[0];
    const float* x2 = (const float*)d_in[1];
    const float* Ws = (const float*)d_in[2];   // [4,2048,2048]
    const float* bs = (const float*)d_in[3];   // [4,2048]
    const float* Wl = (const float*)d_in[4];   // [1024,2048]
    const float* bl = (const float*)d_in[5];   // [1024]
    float* out = (float*)d_out;                // [16384,1024]

    char* ws = (char*)d_ws;
    unsigned short* hA  = (unsigned short*)(ws);                  // 64 MiB
    unsigned short* hB  = (unsigned short*)(ws + (67108864L));    // 64 MiB
    unsigned short* Wbf = (unsigned short*)(ws + (134217728L));   // 32 MiB
    unsigned short* Wlb = (unsigned short*)(ws + (167772160L));   // 4 MiB

    cvt_kernel<<<2048, 256, 0, stream>>>(Ws, Wbf, 4L * 2048 * 2048 / 4);
    cvt_kernel<<<512, 256, 0, stream>>>(Wl, Wlb, 1024L * 2048 / 4);

    attn_kernel<<<16384 / 4, 256, 0, stream>>>(x1, x2, hA);

    // MLP: 4x relu GEMM (bf16 ping-pong) + final GEMM (f32 out)
    gemm256<true, unsigned short><<<512, 512, 0, stream>>>(hA, Wbf + 0L * 2048 * 2048, bs + 0 * 2048, hB, 2048, 2048);
    gemm256<true, unsigned short><<<512, 512, 0, stream>>>(hB, Wbf + 1L * 2048 * 2048, bs + 1 * 2048, hA, 2048, 2048);
    gemm256<true, unsigned short><<<512, 512, 0, stream>>>(hA, Wbf + 2L * 2048 * 2048, bs + 2 * 2048, hB, 2048, 2048);
    gemm256<true, unsigned short><<<512, 512, 0, stream>>>(hB, Wbf + 3L * 2048 * 2048, bs + 3 * 2048, hA, 2048, 2048);
    gemm256<false, float><<<256, 512, 0, stream>>>(hA, Wlb, bl, out, 1024, 2048);
}

// Round 13
// 597.903 us; speedup vs baseline: 1.4218x; 1.0549x over previous
//
#include <hip/hip_runtime.h>

// ---------------- types ----------------
typedef __bf16 bf16x8 __attribute__((ext_vector_type(8)));
typedef float f32x4 __attribute__((ext_vector_type(4)));

__device__ __forceinline__ unsigned short f2bf(float f) {
    unsigned int u = __builtin_bit_cast(unsigned int, f);
    u += 0x7FFFu + ((u >> 16) & 1u);
    return (unsigned short)(u >> 16);
}

// ---------------- weight f32 -> bf16 conversion ----------------
__global__ void cvt_kernel(const float* __restrict__ in,
                           unsigned short* __restrict__ out, long n4) {
    long i = (long)blockIdx.x * blockDim.x + threadIdx.x;
    long stride = (long)gridDim.x * blockDim.x;
    for (; i < n4; i += stride) {
        float4 v = ((const float4*)in)[i];
        ushort4 o;
        o.x = f2bf(v.x); o.y = f2bf(v.y); o.z = f2bf(v.z); o.w = f2bf(v.w);
        ((ushort4*)out)[i] = o;
    }
}

// ---------------- fused 2-token attention -> h0 (bf16) ----------------
__global__ __launch_bounds__(256) void attn_kernel(
    const float* __restrict__ x1, const float* __restrict__ x2,
    unsigned short* __restrict__ h) {
    const int D = 1024;
    const int lane = threadIdx.x & 63;
    const int wave = threadIdx.x >> 6;
    const long row = (long)blockIdx.x * 4 + wave;
    const float4* p1 = (const float4*)(x1 + row * D);
    const float4* p2 = (const float4*)(x2 + row * D);
    float4 v1[4], v2[4];
    float s11 = 0.f, s12 = 0.f, s22 = 0.f;
#pragma unroll
    for (int j = 0; j < 4; ++j) {
        v1[j] = p1[lane + 64 * j];
        v2[j] = p2[lane + 64 * j];
        s11 += v1[j].x * v1[j].x + v1[j].y * v1[j].y + v1[j].z * v1[j].z + v1[j].w * v1[j].w;
        s12 += v1[j].x * v2[j].x + v1[j].y * v2[j].y + v1[j].z * v2[j].z + v1[j].w * v2[j].w;
        s22 += v2[j].x * v2[j].x + v2[j].y * v2[j].y + v2[j].z * v2[j].z + v2[j].w * v2[j].w;
    }
#pragma unroll
    for (int off = 1; off < 64; off <<= 1) {
        s11 += __shfl_xor(s11, off);
        s12 += __shfl_xor(s12, off);
        s22 += __shfl_xor(s22, off);
    }
    const float a00 = 1.f / (1.f + expf((s12 - s11) * (1.f / 32.f)));
    const float a10 = 1.f / (1.f + expf((s22 - s12) * (1.f / 32.f)));
    const float a01 = 1.f - a00, a11 = 1.f - a10;
    unsigned short* h0 = h + row * 2048;
#pragma unroll
    for (int j = 0; j < 4; ++j) {
        const int f = lane + 64 * j;
        ushort4 o0, o1;
        o0.x = f2bf(a00 * v1[j].x + a01 * v2[j].x);
        o0.y = f2bf(a00 * v1[j].y + a01 * v2[j].y);
        o0.z = f2bf(a00 * v1[j].z + a01 * v2[j].z);
        o0.w = f2bf(a00 * v1[j].w + a01 * v2[j].w);
        o1.x = f2bf(a10 * v1[j].x + a11 * v2[j].x);
        o1.y = f2bf(a10 * v1[j].y + a11 * v2[j].y);
        o1.z = f2bf(a10 * v1[j].z + a11 * v2[j].z);
        o1.w = f2bf(a10 * v1[j].w + a11 * v2[j].w);
        ((ushort4*)(h0))[f] = o0;
        ((ushort4*)(h0 + 1024))[f] = o1;
    }
}

// ------------- 256x256 GEMM, 1-stage/1-barrier phases ----------------------
// 8 regions of 16 KiB (2 slots x {A,B} x {kh0,kh1}), K-split halves, 64B
// pitch, st_16x32 swizzle (stage source + read addr). Rotation: each phase
// stages EXACTLY ONE region whose last reader was 2 phases ago (single-
// barrier skew bound = race-free), reads this phase's frags BEFORE the
// barrier (port overlaps previous MFMA pipe drain), counted VMW(8) BEFORE
// the barrier publishes 4-6-phase-old stage retirement to all waves.
// No setprio (m190: hurts lockstep GEMM).
#define BAR   __builtin_amdgcn_s_barrier()
#define LGKM0 do { asm volatile("s_waitcnt lgkmcnt(0)" ::: "memory"); \
                   __builtin_amdgcn_sched_barrier(0); } while (0)
#define VMW(n) asm volatile("s_waitcnt vmcnt(" #n ")" ::: "memory")

#define MMQ(mb)                                                                \
  _Pragma("unroll") for (int n = 0; n < 4; ++n)                                \
  _Pragma("unroll") for (int mq = 0; mq < 4; ++mq)                             \
    acc[(mb) + mq][n] = __builtin_amdgcn_mfma_f32_16x16x32_bf16(               \
        Bf[n], Af[mq], acc[(mb) + mq][n], 0, 0, 0);

template <bool RELU, typename OT>
__global__ __launch_bounds__(512, 2) void gemm256(
    const unsigned short* __restrict__ A,   // [M,K] bf16 (activations)
    const unsigned short* __restrict__ Bw,  // [N,K] bf16 (weights)
    const float* __restrict__ bias,         // [N]
    OT* __restrict__ C,                     // [M,N]
    int N, int K) {
    __shared__ __align__(16) unsigned short lds[65536];  // 128 KiB
    const int tid = threadIdx.x;
    const int lane = tid & 63, wave = tid >> 6;
    const int wm = wave >> 2, wn = wave & 3;
    const int fr = lane & 15, fq = lane >> 4;

    // XCD M-ownership swizzle (R12, proven: FETCH 270->98 MB)
    const int nbn = N >> 8;
    const int sh = (nbn == 8) ? 3 : 2;
    const int cpx = (int)gridDim.x >> 3;
    const int swz = ((int)blockIdx.x & 7) * cpx + ((int)blockIdx.x >> 3);
    const int bn = swz & (nbn - 1);
    const int bm = swz >> sh;
    const long m0 = (long)bm * 256, n0 = (long)bn * 256;
    const long rowb = (long)K * 2;

    // read addressing: region + row*64 + (fq*16 ^ st_16x32 flip)
    const int flip = ((fr >> 3) & 1) << 5;
    const int lbase = fr * 64 + ((fq * 16) ^ flip);
    const int aRd = wm * 8192 + lbase;           // + mh*4096 + mq*1024
    const int bRd = 32768 + wn * 4096 + lbase;   // + nf*1024
    const char* ldsc = (const char*)lds;

    // stage addressing (linear LDS dest, pre-swizzled global source)
    const int srow = wave * 16 + (lane >> 2);              // + L*128
    const int scol = ((lane & 3) << 4) ^ ((lane >> 5) << 5);
    const char* Abl = (const char*)A + m0 * rowb;
    const char* Bbl = (const char*)Bw + n0 * rowb;

    auto stage = [&](const char* mb, int regbase, int kh, int kt) {
#pragma unroll
        for (int L = 0; L < 2; ++L) {
            const int r = L * 128 + srow;
            const char* src = mb + (long)r * rowb + kt * 128 + kh * 64 + scol;
            __builtin_amdgcn_global_load_lds(
                (const __attribute__((address_space(1))) void*)src,
                (__attribute__((address_space(3))) void*)((char*)lds +
                    (regbase + kh * 16384 + L * 8192 + wave * 1024)),
                16, 0, 0);
        }
    };

    f32x4 acc[8][4] = {};
    bf16x8 Bf[4], Af[4];

    auto rdB = [&](int Tb, int kh) {
        const int b = Tb + kh * 16384 + bRd;
#pragma unroll
        for (int nf = 0; nf < 4; ++nf)
            Bf[nf] = *(const bf16x8*)(ldsc + b + nf * 1024);
    };
    auto rdA = [&](int Tb, int kh, int mh) {
        const int b = Tb + kh * 16384 + aRd + mh * 4096;
#pragma unroll
        for (int mq = 0; mq < 4; ++mq)
            Af[mq] = *(const bf16x8*)(ldsc + b + mq * 1024);
    };

    // ---- prologue: S0 all 4 (t0), S1.{B,A}.kh0 (t1) = 6 stage-pairs ----
    stage(Bbl, 32768, 0, 0);          // pro1 S0.B.kh0
    stage(Abl, 0,     0, 0);          // pro2 S0.A.kh0
    stage(Bbl, 32768, 1, 0);          // pro3 S0.B.kh1
    stage(Abl, 0,     1, 0);          // pro4 S0.A.kh1
    stage(Bbl, 65536 + 32768, 0, 1);  // pro5 S1.B.kh0
    stage(Abl, 65536,         0, 1);  // pro6 S1.A.kh0
    VMW(8);                           // retires pro1,pro2 (P1's reads)
    BAR;

    const int NT = K >> 6, NIT = NT >> 1;
    for (int i = 0; i < NIT - 1; ++i) {
        const int u = 2 * i + 1, t2 = 2 * i + 2, t3 = 2 * i + 3;
        // P1: stage S1.B.kh1<-u (last read 2 phases ago); read S0 kh0
        stage(Bbl, 65536 + 32768, 1, u);
        rdB(0, 0); rdA(0, 0, 0);
        VMW(8); BAR; LGKM0; MMQ(0);
        // P2: stage S1.A.kh1<-u; read S0 kh0 mh1
        stage(Abl, 65536, 1, u);
        rdA(0, 0, 1);
        VMW(8); BAR; LGKM0; MMQ(4);
        // P3: stage S0.B.kh0<-t2; read S0 kh1
        stage(Bbl, 32768, 0, t2);
        rdB(0, 1); rdA(0, 1, 0);
        VMW(8); BAR; LGKM0; MMQ(0);
        // P4: stage S0.A.kh0<-t2; read S0 kh1 mh1
        stage(Abl, 0, 0, t2);
        rdA(0, 1, 1);
        VMW(8); BAR; LGKM0; MMQ(4);
        // P5: stage S0.B.kh1<-t2; read S1 kh0
        stage(Bbl, 32768, 1, t2);
        rdB(65536, 0); rdA(65536, 0, 0);
        VMW(8); BAR; LGKM0; MMQ(0);
        // P6: stage S0.A.kh1<-t2; read S1 kh0 mh1
        stage(Abl, 0, 1, t2);
        rdA(65536, 0, 1);
        VMW(8); BAR; LGKM0; MMQ(4);
        // P7: stage S1.B.kh0<-t3; read S1 kh1
        stage(Bbl, 65536 + 32768, 0, t3);
        rdB(65536, 1); rdA(65536, 1, 0);
        VMW(8); BAR; LGKM0; MMQ(0);
        // P8: stage S1.A.kh0<-t3; read S1 kh1 mh1
        stage(Abl, 65536, 0, t3);
        rdA(65536, 1, 1);
        VMW(8); BAR; LGKM0; MMQ(4);
    }
    {   // ---- tail iteration (u = NT-1): stages P3..P8 skipped ----
        const int u = NT - 1;
        stage(Bbl, 65536 + 32768, 1, u);
        rdB(0, 0); rdA(0, 0, 0);
        VMW(8); BAR; LGKM0; MMQ(0);
        stage(Abl, 65536, 1, u);
        rdA(0, 0, 1);
        VMW(8); BAR; LGKM0; MMQ(4);
        rdB(0, 1); rdA(0, 1, 0);
        VMW(8); BAR; LGKM0; MMQ(0);
        rdA(0, 1, 1);
        VMW(4); BAR; LGKM0; MMQ(4);
        rdB(65536, 0); rdA(65536, 0, 0);
        VMW(4); BAR; LGKM0; MMQ(0);
        rdA(65536, 0, 1);
        VMW(0); BAR; LGKM0; MMQ(4);
        rdB(65536, 1); rdA(65536, 1, 0);
        VMW(0); BAR; LGKM0; MMQ(0);
        rdA(65536, 1, 1);
        VMW(0); BAR; LGKM0; MMQ(4);
    }

    // ---- epilogue: swapped layout => lane owns row (fr) x 4 consecutive cols
    const long crow0 = m0 + wm * 128 + fr;
    const long ccol0 = n0 + wn * 64 + fq * 4;
    float4 bv[4];
#pragma unroll
    for (int n = 0; n < 4; ++n) bv[n] = *(const float4*)(bias + ccol0 + n * 16);
#pragma unroll
    for (int m = 0; m < 8; ++m) {
        const long rb = (crow0 + m * 16) * N;
#pragma unroll
        for (int n = 0; n < 4; ++n) {
            float v0 = acc[m][n][0] + bv[n].x;
            float v1 = acc[m][n][1] + bv[n].y;
            float v2 = acc[m][n][2] + bv[n].z;
            float v3 = acc[m][n][3] + bv[n].w;
            if (RELU) {
                v0 = v0 > 0.f ? v0 : 0.f; v1 = v1 > 0.f ? v1 : 0.f;
                v2 = v2 > 0.f ? v2 : 0.f; v3 = v3 > 0.f ? v3 : 0.f;
            }
            if constexpr (sizeof(OT) == 2) {
                uint2 oo;
                oo.x = (unsigned)f2bf(v0) | ((unsigned)f2bf(v1) << 16);
                oo.y = (unsigned)f2bf(v2) | ((unsigned)f2bf(v3) << 16);
                *(uint2*)((unsigned short*)C + rb + ccol0 + n * 16) = oo;
            } else {
                *(float4*)((float*)C + rb + ccol0 + n * 16) =
                    make_float4(v0, v1, v2, v3);
            }
        }
    }
}

// ---------------- launch ----------------
extern "C" void kernel_launch(void* const* d_in, const int* in_sizes, int n_in,
                              void* d_out, int out_size, void* d_ws, size_t ws_size,
                              hipStream_t stream) {
    const float* x1 = (const float*)d_in[0];
    const float* x2 = (const float*)d_in[1];
    const float* Ws = (const float*)d_in[2];   // [4,2048,2048]
    const float* bs = (const float*)d_in[3];   // [4,2048]
    const float* Wl = (const float*)d_in[4];   // [1024,2048]
    const float* bl = (const float*)d_in[5];   // [1024]
    float* out = (float*)d_out;                // [16384,1024]

    char* ws = (char*)d_ws;
    unsigned short* hA  = (unsigned short*)(ws);                  // 64 MiB
    unsigned short* hB  = (unsigned short*)(ws + (67108864L));    // 64 MiB
    unsigned short* Wbf = (unsigned short*)(ws + (134217728L));   // 32 MiB
    unsigned short* Wlb = (unsigned short*)(ws + (167772160L));   // 4 MiB

    cvt_kernel<<<2048, 256, 0, stream>>>(Ws, Wbf, 4L * 2048 * 2048 / 4);
    cvt_kernel<<<512, 256, 0, stream>>>(Wl, Wlb, 1024L * 2048 / 4);

    attn_kernel<<<16384 / 4, 256, 0, stream>>>(x1, x2, hA);

    // MLP: 4x relu GEMM (bf16 ping-pong) + final GEMM (f32 out)
    gemm256<true, unsigned short><<<512, 512, 0, stream>>>(hA, Wbf + 0L * 2048 * 2048, bs + 0 * 2048, hB, 2048, 2048);
    gemm256<true, unsigned short><<<512, 512, 0, stream>>>(hB, Wbf + 1L * 2048 * 2048, bs + 1 * 2048, hA, 2048, 2048);
    gemm256<true, unsigned short><<<512, 512, 0, stream>>>(hA, Wbf + 2L * 2048 * 2048, bs + 2 * 2048, hB, 2048, 2048);
    gemm256<true, unsigned short><<<512, 512, 0, stream>>>(hB, Wbf + 3L * 2048 * 2048, bs + 3 * 2048, hA, 2048, 2048);
    gemm256<false, float><<<256, 512, 0, stream>>>(hA, Wlb, bl, out, 1024, 2048);
}